// Round 8
// baseline (210.127 us; speedup 1.0000x reference)
//
#include <hip/hip_runtime.h>
#include <hip/hip_bf16.h>
#include <stdint.h>

typedef unsigned short u16;
typedef __attribute__((ext_vector_type(8))) __bf16 bvec8;
typedef __attribute__((ext_vector_type(4))) float f32x4;
typedef __attribute__((ext_vector_type(16))) float f32x16;

__device__ __forceinline__ u16 f32_to_bf16(float f) {
    uint32_t u = __float_as_uint(f);
    u += 0x7fffu + ((u >> 16) & 1u);   // RNE
    return (u16)(u >> 16);
}
__device__ __forceinline__ uint32_t pack_bf16x2(float lo, float hi) {
    union { __hip_bfloat162 h; uint32_t u; } c;
    c.h = __float22bfloat162_rn(make_float2(lo, hi));   // x -> low 16 bits
    return c.u;
}

// async global->LDS, 16B/lane; LDS dest = wave-uniform base + lane*16 (HW rule)
__device__ __forceinline__ void gl2lds16(const u16* g, u16* l) {
    void* gnc = const_cast<void*>((const void*)g);
    __builtin_amdgcn_global_load_lds(
        (__attribute__((address_space(1))) uint32_t*)gnc,
        (__attribute__((address_space(3))) uint32_t*)((void*)l),
        16, 0, 0);
}

// ---------------------------------------------------------------------------
// fp32 -> bf16 for all three inputs in one launch
// ---------------------------------------------------------------------------
__global__ __launch_bounds__(256) void cvt3(
    const float* __restrict__ a, int na4, const float* __restrict__ b, int nb4,
    const float* __restrict__ c, int nc4,
    u16* __restrict__ oa, u16* __restrict__ ob, u16* __restrict__ oc)
{
    int i = blockIdx.x * 256 + threadIdx.x;
    const float* src; u16* dst; int off;
    if (i < na4)             { src = a; dst = oa; off = i; }
    else if (i < na4 + nb4)  { src = b; dst = ob; off = i - na4; }
    else if (i < na4 + nb4 + nc4) { src = c; dst = oc; off = i - na4 - nb4; }
    else return;
    float4 v = ((const float4*)src)[off];
    ushort4 o;
    o.x = f32_to_bf16(v.x); o.y = f32_to_bf16(v.y);
    o.z = f32_to_bf16(v.z); o.w = f32_to_bf16(v.w);
    ((ushort4*)dst)[off] = o;
}

// ---------------------------------------------------------------------------
// GEMM (B^T): C[M][N] = A[M][K]*B[N][K]^T + bias[N]; bf16 in, fp32 acc.
// BM=128, BK=32, BNt template (128 or 64). 256 thr = 4 waves as 2x2.
// ---------------------------------------------------------------------------
template <int BNt, bool OUT_BF16>
__global__ __launch_bounds__(256) void gemm_bt_bias(
    const u16* __restrict__ A, const u16* __restrict__ B,
    const float* __restrict__ bias, void* __restrict__ Cv,
    int M, int N, int K)
{
    constexpr int NT = BNt / 32;
    __shared__ __attribute__((aligned(16))) u16 As[128 * 32];
    __shared__ __attribute__((aligned(16))) u16 Bs[BNt * 32];

    const int tid = threadIdx.x, wave = tid >> 6, lane = tid & 63;
    const int col = lane & 15, quad = lane >> 4;
    const int m0 = blockIdx.y * 128, n0 = blockIdx.x * BNt;
    const int wm = (wave >> 1) * 64, wn = (wave & 1) * (BNt / 2);
    const int srow = lane >> 2, schunk = lane & 3;
    const u16* Ag = A + (size_t)(m0 + wave * 32) * K;

    f32x4 acc[4][NT];
#pragma unroll
    for (int i = 0; i < 4; i++)
#pragma unroll
        for (int j = 0; j < NT; j++) acc[i][j] = f32x4{0.f, 0.f, 0.f, 0.f};

    for (int k0 = 0; k0 < K; k0 += 32) {
        __syncthreads();
        gl2lds16(Ag + (size_t)(srow)      * K + k0 + schunk * 8, &As[(wave * 2 + 0) * 512]);
        gl2lds16(Ag + (size_t)(16 + srow) * K + k0 + schunk * 8, &As[(wave * 2 + 1) * 512]);
        if constexpr (BNt == 128) {
            const u16* Bg = B + (size_t)(n0 + wave * 32) * K;
            gl2lds16(Bg + (size_t)(srow)      * K + k0 + schunk * 8, &Bs[(wave * 2 + 0) * 512]);
            gl2lds16(Bg + (size_t)(16 + srow) * K + k0 + schunk * 8, &Bs[(wave * 2 + 1) * 512]);
        } else {
            const u16* Bg = B + (size_t)(n0 + wave * 16) * K;
            gl2lds16(Bg + (size_t)(srow)      * K + k0 + schunk * 8, &Bs[wave * 512]);
        }
        __syncthreads();

        bvec8 af[4], bfv[NT];
#pragma unroll
        for (int mt = 0; mt < 4; mt++)  af[mt]  = *(const bvec8*)&As[(wm + mt * 16 + col) * 32 + quad * 8];
#pragma unroll
        for (int nt = 0; nt < NT; nt++) bfv[nt] = *(const bvec8*)&Bs[(wn + nt * 16 + col) * 32 + quad * 8];
#pragma unroll
        for (int mt = 0; mt < 4; mt++)
#pragma unroll
            for (int nt = 0; nt < NT; nt++)
                acc[mt][nt] = __builtin_amdgcn_mfma_f32_16x16x32_bf16(af[mt], bfv[nt], acc[mt][nt], 0, 0, 0);
    }

#pragma unroll
    for (int mt = 0; mt < 4; mt++) {
#pragma unroll
        for (int r = 0; r < 4; r++) {
            const int m = m0 + wm + mt * 16 + quad * 4 + r;
#pragma unroll
            for (int nt = 0; nt < NT; nt++) {
                const int n = n0 + wn + nt * 16 + col;
                float v = acc[mt][nt][r] + bias[n];
                if (OUT_BF16) ((u16*)Cv)[(size_t)m * N + n] = f32_to_bf16(v);
                else          ((float*)Cv)[(size_t)m * N + n] = v;
            }
        }
    }
}

// ---------------------------------------------------------------------------
// V transpose with sigma-interleave: vT[b][h][d][64*blk + p] = V[64*blk + s(p)][d]
// where s(p) = (p&32) | ((p&1)<<4) | ((p>>1)&15)  (pairs (s,s+16) adjacent)
// ---------------------------------------------------------------------------
__global__ __launch_bounds__(256) void transpose_v(const u16* __restrict__ qkv,
                                                   u16* __restrict__ vT)
{
    __shared__ u16 Ts[64 * 74];
    const int tid = threadIdx.x;
    const int t0 = blockIdx.x * 64, h = blockIdx.y, b = blockIdx.z;
    const u16* src = qkv + (size_t)b * 2048 * 3072 + 2048 + h * 64;
#pragma unroll
    for (int k2 = 0; k2 < 2; k2++) {
        int c = k2 * 256 + tid, tl = c >> 3, ch = c & 7;
        *(uint4*)&Ts[tl * 74 + ch * 8] = *(const uint4*)(src + (size_t)(t0 + tl) * 3072 + ch * 8);
    }
    __syncthreads();
    u16* dst = vT + (size_t)((b * 16 + h) * 64) * 2048;
#pragma unroll
    for (int k2 = 0; k2 < 2; k2++) {
        int c = k2 * 256 + tid, d = c >> 3, tch = c & 7;
        u16 tmp[8];
#pragma unroll
        for (int j2 = 0; j2 < 8; j2++) {
            int p  = tch * 8 + j2;
            int sl = (p & 32) | ((p & 1) << 4) | ((p >> 1) & 15);
            tmp[j2] = Ts[sl * 74 + d];
        }
        *(uint4*)&dst[(size_t)d * 2048 + t0 + tch * 8] = *(const uint4*)tmp;
    }
}

// ---------------------------------------------------------------------------
// Flash attention, BQ=128: 4 waves each own 32 q-rows x full 64-s tile.
// 32x32x16 MFMA, S^T orientation, in-register sigma-pack P->A-frag.
// FIX vs R7: mask gate compares tile s-max against the wave's MIN q (qmin),
// not max q — odd waves' penultimate tiles were passing unmasked.
// ---------------------------------------------------------------------------
__global__ __launch_bounds__(256) void attn_kernel(const u16* __restrict__ qkv,
                                                   const u16* __restrict__ vT,
                                                   u16* __restrict__ Y)
{
    __shared__ __attribute__((aligned(16))) u16 Qs[128 * 64];
    __shared__ __attribute__((aligned(16))) u16 Ks[2][64 * 64];
    __shared__ __attribute__((aligned(16))) u16 Vs[2][64 * 64];
    __shared__ __attribute__((aligned(16))) float Lbuf[4][32];

    const int tid = threadIdx.x, wave = tid >> 6, lane = tid & 63;
    const int l31 = lane & 31, hi = lane >> 5;

    const int g = blockIdx.x;                 // b*16 + h
    const int b = g >> 4, h = g & 15;
    const int j = blockIdx.y;
    const int qt = (j < 8) ? j : (23 - j);    // complementary across +256
    const int q0 = qt * 128;
    const int nkt = 2 * qt + 2;

    const u16* qb = qkv + (size_t)b * 2048 * 3072;
    const u16* vb = vT + (size_t)g * 64 * 2048;

    // ---- stage Q (128x64), 4 DMA calls per wave, XOR chunk swizzle ----
#pragma unroll
    for (int g4 = 0; g4 < 4; g4++) {
        int c = g4 * 256 + wave * 64 + lane;
        int r = c >> 3, ch = c & 7;
        gl2lds16(qb + (size_t)(q0 + r) * 3072 + h * 64 + ((ch ^ (r & 7)) * 8),
                 &Qs[g4 * 2048 + wave * 512]);
    }
    // K/V staging params (64-row tiles)
    const int c0 = wave * 64 + lane, c1 = 256 + c0;
    const int r0 = c0 >> 3, r1 = c1 >> 3;
    const int sw0 = ((c0 & 7) ^ (r0 & 7)) * 8, sw1 = ((c1 & 7) ^ (r1 & 7)) * 8;

    // prologue: K/V tile 0 into buffer 0
    gl2lds16(qb + (size_t)(r0) * 3072 + 1024 + h * 64 + sw0, &Ks[0][wave * 512]);
    gl2lds16(qb + (size_t)(r1) * 3072 + 1024 + h * 64 + sw1, &Ks[0][2048 + wave * 512]);
    gl2lds16(vb + (size_t)r0 * 2048 + sw0, &Vs[0][wave * 512]);
    gl2lds16(vb + (size_t)r1 * 2048 + sw1, &Vs[0][2048 + wave * 512]);
    asm volatile("s_waitcnt vmcnt(4)" ::: "memory");   // Q landed; K0/V0 in flight
    asm volatile("s_barrier" ::: "memory");

    // Q B-fragments (n=q, k=d), persistent
    const int q_lane = wave * 32 + l31;
    bvec8 qf[4];
#pragma unroll
    for (int c = 0; c < 4; c++)
        qf[c] = *(const bvec8*)&Qs[q_lane * 64 + (((c * 2 + hi) ^ (q_lane & 7)) * 8)];

    const int qmin  = q0 + wave * 32;        // min q-row this wave owns
    const int qmax  = qmin + 31;             // max q-row this wave owns
    const int q_act = qmin + l31;            // q owned by this lane (S^T col)

    float l_acc = 0.f;
    f32x16 o0, o1;
#pragma unroll
    for (int i = 0; i < 16; i++) { o0[i] = 0.f; o1[i] = 0.f; }

    for (int kt = 0; kt < nkt; ++kt) {
        const int cur = kt & 1;
        if (kt + 1 < nkt) {
            const int s0n = (kt + 1) * 64, nb2 = cur ^ 1;
            gl2lds16(qb + (size_t)(s0n + r0) * 3072 + 1024 + h * 64 + sw0, &Ks[nb2][wave * 512]);
            gl2lds16(qb + (size_t)(s0n + r1) * 3072 + 1024 + h * 64 + sw1, &Ks[nb2][2048 + wave * 512]);
            gl2lds16(vb + (size_t)r0 * 2048 + s0n + sw0, &Vs[nb2][wave * 512]);
            gl2lds16(vb + (size_t)r1 * 2048 + s0n + sw1, &Vs[nb2][2048 + wave * 512]);
            asm volatile("s_waitcnt vmcnt(4)" ::: "memory");
        } else {
            asm volatile("s_waitcnt vmcnt(0)" ::: "memory");
        }
        asm volatile("s_barrier" ::: "memory");

        const int s_t0 = kt * 64;
        if (s_t0 <= qmax) {                  // else: tile fully above diagonal for this wave
            // S^T = K * Q^T : two 32x32 tiles (s-halves), independent chains
            f32x16 sv0, sv1;
#pragma unroll
            for (int i = 0; i < 16; i++) { sv0[i] = 0.f; sv1[i] = 0.f; }
#pragma unroll
            for (int c = 0; c < 4; c++) {
                bvec8 kf = *(const bvec8*)&Ks[cur][l31 * 64 + (((c * 2 + hi) ^ (l31 & 7)) * 8)];
                sv0 = __builtin_amdgcn_mfma_f32_32x32x16_bf16(kf, qf[c], sv0, 0, 0, 0);
            }
#pragma unroll
            for (int c = 0; c < 4; c++) {
                const int rr = 32 + l31;
                bvec8 kf = *(const bvec8*)&Ks[cur][rr * 64 + (((c * 2 + hi) ^ (rr & 7)) * 8)];
                sv1 = __builtin_amdgcn_mfma_f32_32x32x16_bf16(kf, qf[c], sv1, 0, 0, 0);
            }

            // p = exp(S/8); causal mask whenever tile s-range can exceed qmin
            const bool msk = (s_t0 + 63 > qmin);   // FIX: qmin, not qmax
            float pv0[16], pv1[16];
#pragma unroll
            for (int i = 0; i < 16; i++) {
                float p0 = __expf(sv0[i] * 0.125f);
                float p1 = __expf(sv1[i] * 0.125f);
                if (msk) {
                    const int srow = s_t0 + (i & 3) + 8 * (i >> 2) + 4 * hi;
                    if (srow > q_act)      p0 = 0.f;
                    if (srow + 32 > q_act) p1 = 0.f;
                }
                pv0[i] = p0; pv1[i] = p1;
                l_acc += p0 + p1;
            }

            // sigma-pack (s, s+16) pairs -> PV A-frags, all in-register
            union { uint32_t u[4]; bvec8 v; } pf[4];
#pragma unroll
            for (int i2 = 0; i2 < 4; i2++) {
                pf[0].u[i2] = pack_bf16x2(pv0[i2],     pv0[i2 + 8]);
                pf[1].u[i2] = pack_bf16x2(pv0[i2 + 4], pv0[i2 + 12]);
                pf[2].u[i2] = pack_bf16x2(pv1[i2],     pv1[i2 + 8]);
                pf[3].u[i2] = pack_bf16x2(pv1[i2 + 4], pv1[i2 + 12]);
            }

            // O += P * Vsigma : D[m=q][n=d], two d-tiles, 4 k-chunks each
#pragma unroll
            for (int jc = 0; jc < 4; jc++) {
                const int lc = jc * 2 + hi;
                bvec8 vf0 = *(const bvec8*)&Vs[cur][l31 * 64 + ((lc ^ (l31 & 7)) * 8)];
                o0 = __builtin_amdgcn_mfma_f32_32x32x16_bf16(pf[jc].v, vf0, o0, 0, 0, 0);
                const int rr = 32 + l31;
                bvec8 vf1 = *(const bvec8*)&Vs[cur][rr * 64 + ((lc ^ (rr & 7)) * 8)];
                o1 = __builtin_amdgcn_mfma_f32_32x32x16_bf16(pf[jc].v, vf1, o1, 0, 0, 0);
            }
        }
        asm volatile("s_barrier" ::: "memory");   // readers done before buf reuse
    }

    // ---- epilogue: l broadcast within wave, normalize, store ----
    l_acc += __shfl_xor(l_acc, 32);               // combine the two s-subsets of q=l31
    if (hi == 0) Lbuf[wave][l31] = l_acc;          // same-wave LDS RAW: DS pipe in-order
    float inv[16];
#pragma unroll
    for (int g4 = 0; g4 < 4; g4++) {
        f32x4 lv = *(const f32x4*)&Lbuf[wave][g4 * 8 + 4 * hi];
#pragma unroll
        for (int jj = 0; jj < 4; jj++) inv[g4 * 4 + jj] = 1.0f / lv[jj];
    }
#pragma unroll
    for (int g4 = 0; g4 < 4; g4++) {
#pragma unroll
        for (int jj = 0; jj < 4; jj++) {
            const int i = g4 * 4 + jj;
            const int t = q0 + wave * 32 + g4 * 8 + 4 * hi + jj;
            u16* yrow = Y + (size_t)(b * 2048 + t) * 1024 + h * 64;
            yrow[l31]      = f32_to_bf16(o0[i] * inv[i]);
            yrow[32 + l31] = f32_to_bf16(o1[i] * inv[i]);
        }
    }
}

// ---------------------------------------------------------------------------
extern "C" void kernel_launch(void* const* d_in, const int* in_sizes, int n_in,
                              void* d_out, int out_size, void* d_ws, size_t ws_size,
                              hipStream_t stream) {
    const float* x      = (const float*)d_in[0];
    const float* w_attn = (const float*)d_in[1];
    const float* b_attn = (const float*)d_in[2];
    const float* w_proj = (const float*)d_in[3];
    const float* b_proj = (const float*)d_in[4];
    float* out = (float*)d_out;

    u16* xb  = (u16*)d_ws;
    u16* wab = xb  + (size_t)4096 * 1024;
    u16* wpb = wab + (size_t)3072 * 1024;
    u16* qkv = wpb + (size_t)1024 * 1024;
    u16* y   = qkv + (size_t)4096 * 3072;
    u16* vT  = xb;                               // reuse: dead after GEMM1

    const int na4 = 4096 * 1024 / 4, nb4 = 3072 * 1024 / 4, nc4 = 1024 * 1024 / 4;
    cvt3<<<(na4 + nb4 + nc4 + 255) / 256, 256, 0, stream>>>(
        x, na4, w_attn, nb4, w_proj, nc4, xb, wab, wpb);

    dim3 g1(3072 / 128, 4096 / 128);
    gemm_bt_bias<128, true><<<g1, 256, 0, stream>>>(xb, wab, b_attn, qkv, 4096, 3072, 1024);

    dim3 gt(32, 16, 2);
    transpose_v<<<gt, 256, 0, stream>>>(qkv, vT);

    dim3 g2(32, 16, 1);   // x = b*16+h (XCD-local K/V), y = q-tile slot
    attn_kernel<<<g2, 256, 0, stream>>>(qkv, vT, y);

    dim3 g3(1024 / 64, 4096 / 128);
    gemm_bt_bias<64, false><<<g3, 256, 0, stream>>>(y, wpb, b_proj, out, 4096, 1024, 1024);
}